// Round 5
// baseline (1881.344 us; speedup 1.0000x reference)
//
#include <hip/hip_runtime.h>
#include <math.h>

#define DIM   128
#define NV    (DIM*DIM*DIM)          // elements per volume; 4 volumes
#define SM    1e-6f
#define NITER 40
#define INV27 (1.0f/27.0f)
#define ACC_OFF  96
#define FLAG_OFF 104
#define BUF_OFF  256                 // floats offset into ws for buffers
#define YT 20                        // thread rows (16 interior + 2 halo each side)
#define ZC 4                         // z outputs per block

typedef _Float16 half8 __attribute__((ext_vector_type(8)));

__device__ __forceinline__ float c01(float v){ return fminf(fmaxf(v, 0.f), 1.f); }

__global__ __launch_bounds__(256)
void k_init_meta(float* meta) { meta[threadIdx.x] = 0.0f; }

__global__ __launch_bounds__(256)
void k_flag(const float4* __restrict__ pred, float* __restrict__ meta, int n4) {
    int stride = gridDim.x * blockDim.x;
    bool hit = false;
    for (int i = blockIdx.x * blockDim.x + threadIdx.x; i < n4; i += stride) {
        float4 p = pred[i];
        hit |= (p.x > 1.f) | (p.y > 1.f) | (p.z > 1.f) | (p.w > 1.f);
    }
    if (hit) meta[FLAG_OFF] = 1.0f;   // same-value racing stores: benign
}

// clip(+optional sigmoid) fp32 inputs -> fp16 buffers. 8 elements/thread.
__global__ __launch_bounds__(256)
void k_prep(const float* __restrict__ pred, const float* __restrict__ tgt,
            const float* __restrict__ meta, _Float16* __restrict__ outP,
            _Float16* __restrict__ outT) {
    const bool sg = (meta[FLAG_OFF] != 0.0f);
    const int idx = blockIdx.x * blockDim.x + threadIdx.x;   // < 2*NV/8
    const int i8 = idx * 8;
    float4 a = *(const float4*)(pred + i8);
    float4 b = *(const float4*)(pred + i8 + 4);
    float pv[8] = {a.x,a.y,a.z,a.w,b.x,b.y,b.z,b.w};
    half8 hp, ht;
    #pragma unroll
    for (int k = 0; k < 8; ++k) {
        float p = pv[k];
        if (sg) p = 1.f / (1.f + __expf(-p));
        hp[k] = (_Float16)c01(p);
    }
    *(half8*)(outP + i8) = hp;
    float4 c = *(const float4*)(tgt + i8);
    float4 d = *(const float4*)(tgt + i8 + 4);
    float tv[8] = {c.x,c.y,c.z,c.w,d.x,d.y,d.z,d.w};
    #pragma unroll
    for (int k = 0; k < 8; ++k) ht[k] = (_Float16)c01(tv[k]);
    *(half8*)(outT + i8) = ht;
}

// Fused skeletonize step, fp16 storage / fp32 math, 1 barrier per plane,
// depth-2 register prefetch queue (load stays in flight across 2 barriers).
__global__ __launch_bounds__(320)
void k_step(const _Float16* __restrict__ src, _Float16* __restrict__ dst,
            float* __restrict__ sums, int iter) {
    __shared__ float4 sA4[2][YT][33];   // input row-sums
    __shared__ float4 sB4[2][YT][33];   // eroded row-sums
    __shared__ float  sRed[5];
    __shared__ float  sDone;

    const int x    = threadIdx.x;          // 0..15
    const int y    = threadIdx.y;          // 0..19
    const int tid  = y * 16 + x;
    const int lane = tid & 63;
    const int ytile = blockIdx.x & 7;
    const int zch   = blockIdx.x >> 3;     // 0..31
    const int vol   = blockIdx.y;          // 0,1 pred; 2,3 target
    const int g     = vol >> 1;
    const int z0    = zch * ZC;
    const int gy    = ytile * 16 - 2 + y;
    const bool rowIn = (gy >= 0) && (gy < DIM);
    const bool midY  = (y >= 1) && (y <= 18);
    const bool outY  = (y >= 2) && (y <= 17);

    if (tid < 64) {
        bool hit = (tid < iter) && (sums[tid * 2 + g] < SM);
        unsigned long long m = __ballot(hit);
        if (lane == 0) sDone = (m != 0ull) ? 1.0f : 0.0f;
    }
    __syncthreads();
    const bool done = (sDone != 0.0f);

    const _Float16* sp = src + (size_t)vol * NV + (size_t)gy * DIM + x * 8;
    _Float16*       dp = dst + (size_t)vol * NV + (size_t)gy * DIM + x * 8;

    float vm1[8] = {0}, vm2[8] = {0}, vm3[8] = {0};
    float s1[8] = {0}, s2[8] = {0};
    float r2[8] = {0};
    float g1[8] = {0}, g2[8] = {0};
    float localSum = 0.f;

    // depth-2 prefetch queue: hv = plane Z, hn1 = Z+1, hn2 = Z+2
    half8 hv = (half8)(_Float16)0.f, hn1 = hv, hn2 = hv;
    if (rowIn) {
        if (z0 - 2 >= 0) hv  = *(const half8*)(sp + (size_t)(z0 - 2) * (DIM * DIM));
        if (z0 - 1 >= 0) hn1 = *(const half8*)(sp + (size_t)(z0 - 1) * (DIM * DIM));
        hn2 = *(const half8*)(sp + (size_t)z0 * (DIM * DIM));
    }

    for (int Z = z0 - 2; Z <= z0 + ZC + 2; ++Z) {
        const int p = Z & 1;
        float v[8];
        #pragma unroll
        for (int k = 0; k < 8; ++k) v[k] = (float)hv[k];
        hv = hn1; hn1 = hn2;
        // issue load of plane Z+3 (consumed 3 trips later)
        hn2 = (half8)(_Float16)0.f;
        const int Zn = Z + 3;
        if (rowIn && Zn < DIM && Zn <= z0 + ZC + 1)
            hn2 = *(const half8*)(sp + (size_t)Zn * (DIM * DIM));

        // ---- x row-sum via shuffles ----
        float lft = __shfl(v[7], lane - 1); if (x == 0)  lft = 0.f;
        float rgt = __shfl(v[0], lane + 1); if (x == 15) rgt = 0.f;
        float rs[8];
        rs[0] = lft + v[0] + v[1];
        #pragma unroll
        for (int k = 1; k < 7; ++k) rs[k] = v[k-1] + v[k] + v[k+1];
        rs[7] = v[6] + v[7] + rgt;

        sA4[p][y][x]      = make_float4(rs[0], rs[1], rs[2], rs[3]);
        sA4[p][y][16 + x] = make_float4(rs[4], rs[5], rs[6], rs[7]);
        sB4[p][y][x]      = make_float4(r2[0], r2[1], r2[2], r2[3]);
        sB4[p][y][16 + x] = make_float4(r2[4], r2[5], r2[6], r2[7]);
        __syncthreads();

        const int ym = (y > 0) ? y - 1 : 0;
        const int yp = (y < YT - 1) ? y + 1 : YT - 1;
        float4 uA = sA4[p][ym][x], uB = sA4[p][ym][16 + x];
        float4 dA = sA4[p][yp][x], dB = sA4[p][yp][16 + x];
        float u[8] = {uA.x,uA.y,uA.z,uA.w,uB.x,uB.y,uB.z,uB.w};
        float dn[8] = {dA.x,dA.y,dA.z,dA.w,dB.x,dB.y,dB.z,dB.w};
        float sd[8];
        #pragma unroll
        for (int k = 0; k < 8; ++k) sd[k] = u[k] + rs[k] + dn[k];

        const bool erOk = midY && rowIn && (Z - 1 >= 0) && (Z - 1 < DIM);
        float er[8];
        #pragma unroll
        for (int k = 0; k < 8; ++k) {
            float e = (s2[k] + s1[k] + sd[k]) * INV27 - SM;
            er[k] = erOk ? c01(e) : 0.f;
        }
        #pragma unroll
        for (int k = 0; k < 8; ++k) { s2[k] = s1[k]; s1[k] = sd[k]; }

        // ---- x row-sum of eroded -> r2 for next trip's LDS store ----
        float lft2 = __shfl(er[7], lane - 1); if (x == 0)  lft2 = 0.f;
        float rgt2 = __shfl(er[0], lane + 1); if (x == 15) rgt2 = 0.f;
        float r2n[8];
        r2n[0] = lft2 + er[0] + er[1];
        #pragma unroll
        for (int k = 1; k < 7; ++k) r2n[k] = er[k-1] + er[k] + er[k+1];
        r2n[7] = er[6] + er[7] + rgt2;

        // ---- 2D sum of eroded (plane Z-2) from LDS ----
        float4 euA = sB4[p][ym][x], euB = sB4[p][ym][16 + x];
        float4 edA = sB4[p][yp][x], edB = sB4[p][yp][16 + x];
        float eu[8] = {euA.x,euA.y,euA.z,euA.w,euB.x,euB.y,euB.z,euB.w};
        float ed[8] = {edA.x,edA.y,edA.z,edA.w,edB.x,edB.y,edB.z,edB.w};
        float e2[8];
        #pragma unroll
        for (int k = 0; k < 8; ++k) e2[k] = eu[k] + r2[k] + ed[k];

        // ---- opened plane Z-3, emit ----
        const int zo = Z - 3;
        if (zo >= z0 && outY) {
            half8 ho;
            float part = 0.f;
            #pragma unroll
            for (int k = 0; k < 8; ++k) {
                float op = c01((g2[k] + g1[k] + e2[k]) * INV27);
                float nv = vm3[k] * (1.f - op + SM);
                nv = done ? vm3[k] : nv;
                ho[k] = (_Float16)nv;
                part += nv;
            }
            *(half8*)(dp + (size_t)zo * (DIM * DIM)) = ho;
            localSum += part;
        }
        #pragma unroll
        for (int k = 0; k < 8; ++k) {
            g2[k] = g1[k]; g1[k] = e2[k];
            vm3[k] = vm2[k]; vm2[k] = vm1[k]; vm1[k] = v[k];
            r2[k] = r2n[k];
        }
    }

    // ---- block reduce localSum -> sums[iter*2+g] ----
    float s = localSum;
    for (int off = 32; off > 0; off >>= 1) s += __shfl_down(s, off);
    if (lane == 0) sRed[tid >> 6] = s;
    __syncthreads();
    if (tid == 0)
        atomicAdd(&sums[iter * 2 + g], sRed[0] + sRed[1] + sRed[2] + sRed[3] + sRed[4]);
}

// XCD-matched dice reduction. grid (64, 8): bx = ytile + 8*zc16 ; by = b + 2*zq
__global__ __launch_bounds__(256)
void k_dice(const _Float16* __restrict__ buf, float* __restrict__ acc) {
    __shared__ float sA[4], sB[4], sC[4];
    const int bx = blockIdx.x, by = blockIdx.y;
    const int ytile = bx & 7, zc16 = bx >> 3;
    const int b = by & 1, zq = by >> 1;
    const int y0 = ytile * 16;
    const int z0 = zc16 * 16 + zq * 4;
    const int tid  = threadIdx.x;
    const int lane = tid & 63;
    const int yy = tid >> 4, xg = tid & 15;

    const _Float16* p = buf + (size_t)b * NV;
    const _Float16* t = buf + (size_t)(2 + b) * NV;

    float si = 0.f, spv = 0.f, stv = 0.f;
    #pragma unroll
    for (int zi = 0; zi < 4; ++zi) {
        const size_t off = ((size_t)(z0 + zi) * DIM + (y0 + yy)) * DIM + xg * 8;
        half8 hp = *(const half8*)(p + off);
        half8 ht = *(const half8*)(t + off);
        #pragma unroll
        for (int k = 0; k < 8; ++k) {
            float pv = (float)hp[k], tv = (float)ht[k];
            si += pv * tv; spv += pv; stv += tv;
        }
    }
    for (int off = 32; off > 0; off >>= 1) {
        si  += __shfl_down(si, off);
        spv += __shfl_down(spv, off);
        stv += __shfl_down(stv, off);
    }
    if (lane == 0) { sA[tid >> 6] = si; sB[tid >> 6] = spv; sC[tid >> 6] = stv; }
    __syncthreads();
    if (tid == 0) {
        atomicAdd(&acc[b * 3 + 0], sA[0] + sA[1] + sA[2] + sA[3]);
        atomicAdd(&acc[b * 3 + 1], sB[0] + sB[1] + sB[2] + sB[3]);
        atomicAdd(&acc[b * 3 + 2], sC[0] + sC[1] + sC[2] + sC[3]);
    }
}

__global__ void k_fin(const float* __restrict__ acc, float* __restrict__ out) {
    float loss = 0.0f;
    for (int b = 0; b < 2; ++b) {
        float inter = acc[b * 3 + 0], spv = acc[b * 3 + 1], stv = acc[b * 3 + 2];
        float dice = (2.0f * inter + SM) / (spv + stv + SM);
        loss += 1.0f - dice;
    }
    out[0] = 0.5f * loss;
}

extern "C" void kernel_launch(void* const* d_in, const int* in_sizes, int n_in,
                              void* d_out, int out_size, void* d_ws, size_t ws_size,
                              hipStream_t stream) {
    (void)in_sizes; (void)n_in; (void)out_size; (void)ws_size;
    const float* pred = (const float*)d_in[0];
    const float* tgt  = (const float*)d_in[1];
    float* out  = (float*)d_out;
    float* meta = (float*)d_ws;
    _Float16* bufA = (_Float16*)(meta + BUF_OFF);
    _Float16* bufB = bufA + (size_t)4 * NV;

    k_init_meta<<<dim3(1), dim3(256), 0, stream>>>(meta);
    k_flag<<<dim3(1024), dim3(256), 0, stream>>>((const float4*)pred, meta, 2 * NV / 4);
    k_prep<<<dim3(2 * NV / 8 / 256), dim3(256), 0, stream>>>(
        pred, tgt, meta, bufA, bufA + (size_t)2 * NV);

    dim3 sgrid(8 * (DIM / ZC), 4);   // (ytile + 8*zch, vol) ; XCD = ytile
    dim3 sblock(16, YT);
    for (int it = 0; it < NITER; ++it) {
        const _Float16* s = (it & 1) ? bufB : bufA;
        _Float16*       d = (it & 1) ? bufA : bufB;
        k_step<<<sgrid, sblock, 0, stream>>>(s, d, meta, it);
    }

    k_dice<<<dim3(64, 8), dim3(256), 0, stream>>>(bufA, meta + ACC_OFF);
    k_fin<<<dim3(1), dim3(1), 0, stream>>>(meta + ACC_OFF, out);
}

// Round 6
// 908.388 us; speedup vs baseline: 2.0711x; 2.0711x over previous
//
#include <hip/hip_runtime.h>
#include <math.h>

#define DIM   128
#define NV    (DIM*DIM*DIM)          // elements per volume; 4 volumes
#define SM    1e-6f
#define NITER 40
#define ACC_OFF  96
#define FLAG_OFF 104
#define BUF_OFF  256                 // floats offset into ws for buffers
#define YT 20                        // thread rows (16 interior + 2 halo each side)
#define ZC 8                         // z outputs per block

typedef _Float16 half8 __attribute__((ext_vector_type(8)));

__device__ __forceinline__ float c01(float v){ return fminf(fmaxf(v, 0.f), 1.f); }
__device__ __forceinline__ half8 h8z(){ return (half8)(_Float16)0.f; }

__device__ __forceinline__ _Float16 shflh(_Float16 v, int srcLane){
    unsigned short s = __builtin_bit_cast(unsigned short, v);
    int r = __shfl((int)(unsigned)s, srcLane);
    return __builtin_bit_cast(_Float16, (unsigned short)(r & 0xffff));
}

// 3-point x-sum of an 8-wide fp16 strip, halo via 2 lane shuffles
__device__ __forceinline__ half8 rowsum3(half8 h, int x, int lane){
    _Float16 lft = shflh(h[7], lane - 1); if (x == 0)  lft = (_Float16)0.f;
    _Float16 rgt = shflh(h[0], lane + 1); if (x == 15) rgt = (_Float16)0.f;
    half8 shl, shr;
    shl[0] = lft; shr[7] = rgt;
    #pragma unroll
    for (int k = 1; k < 8; ++k) shl[k] = h[k-1];
    #pragma unroll
    for (int k = 0; k < 7; ++k) shr[k] = h[k+1];
    return shl + h + shr;
}

__device__ __forceinline__ half8 hclip01(half8 v){
    const half8 one  = (half8)(_Float16)1.f;
    const half8 zero = (half8)(_Float16)0.f;
    return __builtin_elementwise_max(__builtin_elementwise_min(v, one), zero);
}

__global__ __launch_bounds__(256)
void k_init_meta(float* meta) { meta[threadIdx.x] = 0.0f; }

__global__ __launch_bounds__(256)
void k_flag(const float4* __restrict__ pred, float* __restrict__ meta, int n4) {
    int stride = gridDim.x * blockDim.x;
    bool hit = false;
    for (int i = blockIdx.x * blockDim.x + threadIdx.x; i < n4; i += stride) {
        float4 p = pred[i];
        hit |= (p.x > 1.f) | (p.y > 1.f) | (p.z > 1.f) | (p.w > 1.f);
    }
    if (hit) meta[FLAG_OFF] = 1.0f;   // same-value racing stores: benign
}

// clip(+optional sigmoid) fp32 inputs -> fp16 buffers. 8 elements/thread.
__global__ __launch_bounds__(256)
void k_prep(const float* __restrict__ pred, const float* __restrict__ tgt,
            const float* __restrict__ meta, _Float16* __restrict__ outP,
            _Float16* __restrict__ outT) {
    const bool sg = (meta[FLAG_OFF] != 0.0f);
    const int idx = blockIdx.x * blockDim.x + threadIdx.x;
    const int i8 = idx * 8;
    float4 a = *(const float4*)(pred + i8);
    float4 b = *(const float4*)(pred + i8 + 4);
    float pv[8] = {a.x,a.y,a.z,a.w,b.x,b.y,b.z,b.w};
    half8 hp, ht;
    #pragma unroll
    for (int k = 0; k < 8; ++k) {
        float p = pv[k];
        if (sg) p = 1.f / (1.f + __expf(-p));
        hp[k] = (_Float16)c01(p);
    }
    *(half8*)(outP + i8) = hp;
    float4 c = *(const float4*)(tgt + i8);
    float4 d = *(const float4*)(tgt + i8 + 4);
    float tv[8] = {c.x,c.y,c.z,c.w,d.x,d.y,d.z,d.w};
    #pragma unroll
    for (int k = 0; k < 8; ++k) ht[k] = (_Float16)c01(tv[k]);
    *(half8*)(outT + i8) = ht;
}

// Fused skeletonize step: packed-fp16 math, 2 planes per barrier,
// 4-slot LDS phase ring. Block 16x20, thread owns 8 contiguous x.
__global__ __launch_bounds__(320)
void k_step(const _Float16* __restrict__ src, _Float16* __restrict__ dst,
            float* __restrict__ sums, int iter) {
    __shared__ half8 sA[4][YT][17];    // input row-sums, phase = plane&3
    __shared__ half8 sB[4][YT][17];    // eroded row-sums, phase = plane&3
    __shared__ float sRed[5];
    __shared__ float sDone;

    const int x    = threadIdx.x;          // 0..15
    const int y    = threadIdx.y;          // 0..19
    const int tid  = y * 16 + x;
    const int lane = tid & 63;
    const int ytile = blockIdx.x & 7;
    const int zch   = blockIdx.x >> 3;     // 0..15
    const int vol   = blockIdx.y;
    const int g     = vol >> 1;
    const int z0    = zch * ZC;
    const int gy    = ytile * 16 - 2 + y;
    const bool rowIn = (gy >= 0) && (gy < DIM);
    const bool midY  = (y >= 1) && (y <= 18);
    const bool outY  = (y >= 2) && (y <= 17);

    if (tid < 64) {
        bool hit = (tid < iter) && (sums[tid * 2 + g] < SM);
        unsigned long long m = __ballot(hit);
        if (lane == 0) sDone = (m != 0ull) ? 1.0f : 0.0f;
    }
    __syncthreads();
    const bool done = (sDone != 0.0f);

    const _Float16* sp = src + (size_t)vol * NV + (size_t)gy * DIM + x * 8;
    _Float16*       dp = dst + (size_t)vol * NV + (size_t)gy * DIM + x * 8;

    const half8 hz = h8z();
    const half8 inv27v = (half8)(_Float16)(1.f/27.f);
    const half8 smv    = (half8)(_Float16)1e-6f;

    half8 vm4 = hz, vm3 = hz, vm2 = hz, vm1 = hz;   // v history (need Z-4, Z-3 at emit)
    half8 s1 = hz, s2 = hz;                          // sd (2D input sum) history
    half8 r2lo = hz, r2hi = hz;                      // rs2(Z-3), rs2(Z-2): stored this trip
    half8 g1 = hz, g2 = hz;                          // e2 history
    float localSum = 0.f;

    auto LD = [&](int P) -> half8 {
        if (rowIn && P >= 0 && P < DIM && P <= z0 + ZC + 1)
            return *(const half8*)(sp + (size_t)P * (DIM * DIM));
        return h8z();
    };

    half8 hvA = LD(z0 - 2), hvB = LD(z0 - 1);   // current pair
    half8 hnA = LD(z0),     hnB = LD(z0 + 1);   // next pair (in flight)

    for (int Z = z0 - 2; Z <= z0 + ZC + 2; Z += 2) {
        const half8 cA = hvA, cB = hvB;
        hvA = hnA; hvB = hnB;
        hnA = LD(Z + 4); hnB = LD(Z + 5);        // consumed 2 trips later

        const bool liveA = (Z     <= z0 + ZC + 1);   // plane's sd/er chain still needed?
        const bool liveB = (Z + 1 <= z0 + ZC + 1);
        const int sa0 = Z & 3, sa1 = (Z + 1) & 3;
        const int sb0 = (Z - 3) & 3, sb1 = (Z - 2) & 3;

        // ---- pre-barrier: row-sums + stores ----
        half8 rsA = hz, rsB = hz;
        if (liveA) { rsA = rowsum3(cA, x, lane); sA[sa0][y][x] = rsA; }
        if (liveB) { rsB = rowsum3(cB, x, lane); sA[sa1][y][x] = rsB; }
        sB[sb0][y][x] = r2lo;
        sB[sb1][y][x] = r2hi;
        __syncthreads();

        const int ym = (y > 0) ? y - 1 : 0;
        const int yp = (y < YT - 1) ? y + 1 : YT - 1;

        // ---- e2 (2D sum of eroded) for planes Z-3, Z-2 ----
        half8 e2lo, e2hi;
        {
            half8 eu = sB[sb0][ym][x], ed = sB[sb0][yp][x];
            e2lo = eu + r2lo + ed;
            half8 fu = sB[sb1][ym][x], fd = sB[sb1][yp][x];
            e2hi = fu + r2hi + fd;
        }

        // ---- sd -> eroded -> rs2 for planes Z-1, Z ----
        half8 r2nlo = hz, r2nhi = hz;
        if (liveA) {
            half8 u = sA[sa0][ym][x], d = sA[sa0][yp][x];
            half8 sd = u + rsA + d;
            half8 er = hz;
            if (midY && rowIn && (Z - 1) >= 0 && (Z - 1) < DIM)
                er = hclip01((s2 + s1 + sd) * inv27v - smv);
            s2 = s1; s1 = sd;
            r2nlo = rowsum3(er, x, lane);
        }
        if (liveB) {
            half8 u = sA[sa1][ym][x], d = sA[sa1][yp][x];
            half8 sd = u + rsB + d;
            half8 er = hz;
            if (midY && rowIn && Z >= 0 && Z < DIM)
                er = hclip01((s2 + s1 + sd) * inv27v - smv);
            s2 = s1; s1 = sd;
            r2nhi = rowsum3(er, x, lane);
        }

        // ---- opened + emit planes Z-4, Z-3 ----
        const int zoA = Z - 4, zoB = Z - 3;
        if (outY && zoA >= z0) {
            half8 op = hclip01((g2 + g1 + e2lo) * inv27v);
            half8 ho; float part = 0.f;
            #pragma unroll
            for (int k = 0; k < 8; ++k) {
                float nv = (float)vm4[k] * (1.f - (float)op[k] + SM);
                nv = done ? (float)vm4[k] : nv;
                ho[k] = (_Float16)nv;
                part += nv;
            }
            *(half8*)(dp + (size_t)zoA * (DIM * DIM)) = ho;
            localSum += part;
        }
        if (outY && zoB >= z0) {
            half8 op = hclip01((g1 + e2lo + e2hi) * inv27v);
            half8 ho; float part = 0.f;
            #pragma unroll
            for (int k = 0; k < 8; ++k) {
                float nv = (float)vm3[k] * (1.f - (float)op[k] + SM);
                nv = done ? (float)vm3[k] : nv;
                ho[k] = (_Float16)nv;
                part += nv;
            }
            *(half8*)(dp + (size_t)zoB * (DIM * DIM)) = ho;
            localSum += part;
        }

        // ---- roll histories ----
        g2 = e2lo; g1 = e2hi;
        r2lo = r2nlo; r2hi = r2nhi;
        vm4 = vm2; vm3 = vm1; vm2 = cA; vm1 = cB;
    }

    // ---- block reduce localSum -> sums[iter*2+g] ----
    float s = localSum;
    for (int off = 32; off > 0; off >>= 1) s += __shfl_down(s, off);
    if (lane == 0) sRed[tid >> 6] = s;
    __syncthreads();
    if (tid == 0)
        atomicAdd(&sums[iter * 2 + g], sRed[0] + sRed[1] + sRed[2] + sRed[3] + sRed[4]);
}

// XCD-matched dice reduction. grid (64, 8): bx = ytile + 8*zc16 ; by = b + 2*zq
__global__ __launch_bounds__(256)
void k_dice(const _Float16* __restrict__ buf, float* __restrict__ acc) {
    __shared__ float sA[4], sB[4], sC[4];
    const int bx = blockIdx.x, by = blockIdx.y;
    const int ytile = bx & 7, zc16 = bx >> 3;
    const int b = by & 1, zq = by >> 1;
    const int y0 = ytile * 16;
    const int z0 = zc16 * 16 + zq * 4;
    const int tid  = threadIdx.x;
    const int lane = tid & 63;
    const int yy = tid >> 4, xg = tid & 15;

    const _Float16* p = buf + (size_t)b * NV;
    const _Float16* t = buf + (size_t)(2 + b) * NV;

    float si = 0.f, spv = 0.f, stv = 0.f;
    #pragma unroll
    for (int zi = 0; zi < 4; ++zi) {
        const size_t off = ((size_t)(z0 + zi) * DIM + (y0 + yy)) * DIM + xg * 8;
        half8 hp = *(const half8*)(p + off);
        half8 ht = *(const half8*)(t + off);
        #pragma unroll
        for (int k = 0; k < 8; ++k) {
            float pv = (float)hp[k], tv = (float)ht[k];
            si += pv * tv; spv += pv; stv += tv;
        }
    }
    for (int off = 32; off > 0; off >>= 1) {
        si  += __shfl_down(si, off);
        spv += __shfl_down(spv, off);
        stv += __shfl_down(stv, off);
    }
    if (lane == 0) { sA[tid >> 6] = si; sB[tid >> 6] = spv; sC[tid >> 6] = stv; }
    __syncthreads();
    if (tid == 0) {
        atomicAdd(&acc[b * 3 + 0], sA[0] + sA[1] + sA[2] + sA[3]);
        atomicAdd(&acc[b * 3 + 1], sB[0] + sB[1] + sB[2] + sB[3]);
        atomicAdd(&acc[b * 3 + 2], sC[0] + sC[1] + sC[2] + sC[3]);
    }
}

__global__ void k_fin(const float* __restrict__ acc, float* __restrict__ out) {
    float loss = 0.0f;
    for (int b = 0; b < 2; ++b) {
        float inter = acc[b * 3 + 0], spv = acc[b * 3 + 1], stv = acc[b * 3 + 2];
        float dice = (2.0f * inter + SM) / (spv + stv + SM);
        loss += 1.0f - dice;
    }
    out[0] = 0.5f * loss;
}

extern "C" void kernel_launch(void* const* d_in, const int* in_sizes, int n_in,
                              void* d_out, int out_size, void* d_ws, size_t ws_size,
                              hipStream_t stream) {
    (void)in_sizes; (void)n_in; (void)out_size; (void)ws_size;
    const float* pred = (const float*)d_in[0];
    const float* tgt  = (const float*)d_in[1];
    float* out  = (float*)d_out;
    float* meta = (float*)d_ws;
    _Float16* bufA = (_Float16*)(meta + BUF_OFF);
    _Float16* bufB = bufA + (size_t)4 * NV;

    k_init_meta<<<dim3(1), dim3(256), 0, stream>>>(meta);
    k_flag<<<dim3(1024), dim3(256), 0, stream>>>((const float4*)pred, meta, 2 * NV / 4);
    k_prep<<<dim3(2 * NV / 8 / 256), dim3(256), 0, stream>>>(
        pred, tgt, meta, bufA, bufA + (size_t)2 * NV);

    dim3 sgrid(8 * (DIM / ZC), 4);   // (ytile + 8*zch, vol) ; XCD = ytile
    dim3 sblock(16, YT);
    for (int it = 0; it < NITER; ++it) {
        const _Float16* s = (it & 1) ? bufB : bufA;
        _Float16*       d = (it & 1) ? bufA : bufB;
        k_step<<<sgrid, sblock, 0, stream>>>(s, d, meta, it);
    }

    k_dice<<<dim3(64, 8), dim3(256), 0, stream>>>(bufA, meta + ACC_OFF);
    k_fin<<<dim3(1), dim3(1), 0, stream>>>(meta + ACC_OFF, out);
}